// Round 3
// baseline (828.081 us; speedup 1.0000x reference)
//
#include <hip/hip_runtime.h>
#include <math.h>

#pragma clang fp contract(off)

#define HW      (2048*2048)
#define NI      4096        // instances per image
#define MAXPIX  1024        // pixels per instance (equal partition)
#define NF      200
#define FEAT    209
#define NE      (NI*2)
#define XSIZE   ((2*NI)*FEAT)
#define EIOFF   XSIZE
#define EAOFF   (EIOFF + 2*NE)

#define CHK     2048        // chunks per image
#define PPC     (HW/CHK)    // 2048 pixels per chunk
#define TOTCHK  (2*CHK)     // 4096
#define NBPI    256         // buckets per image (16 labels each)
#define LPB     16          // labels per bucket
#define NBG     (2*NBPI)    // 512 global buckets
#define REC     (2*HW)      // 16.7M records

template<int NB>
__device__ __forceinline__ unsigned long long match_bits(int v) {
    unsigned long long m = ~0ull;
    #pragma unroll
    for (int bit = 0; bit < NB; ++bit) {
        unsigned long long bb = __ballot((v >> bit) & 1);
        m &= ((v >> bit) & 1) ? bb : ~bb;
    }
    return m;
}

// ---- pass 1: per-chunk per-bucket counts (ballot-match, no 4096-ctr atomics)
__global__ void __launch_bounds__(256) countA_kernel(const int* __restrict__ mask1,
        const int* __restrict__ mask2, unsigned* __restrict__ cntA) {
    __shared__ unsigned cnt[4][NBPI];
    int w = threadIdx.x >> 6, lane = threadIdx.x & 63;
    for (int j = threadIdx.x; j < 4*NBPI; j += 256) ((unsigned*)cnt)[j] = 0u;
    __syncthreads();
    int c = blockIdx.x * 4 + w;
    int img = c / CHK;
    const int* mask = img ? mask2 : mask1;
    long base = (long)(c - img*CHK) * PPC;
    for (int t = 0; t < PPC; t += 64) {
        int l = mask[base + t + lane] - 1;
        int bkt = l >> 4;
        unsigned long long m = match_bits<8>(bkt);
        int cb = __popcll(m & ((1ull << lane) - 1ull));
        if (cb == 0) cnt[w][bkt] += (unsigned)__popcll(m);   // leader, distinct addrs
    }
    unsigned* dst = cntA + (long)c * NBPI;
    for (int j = lane; j < NBPI; j += 64) dst[j] = cnt[w][j];
}

// ---- pass 2a: per-bucket exclusive scan over its chunks ------------------
__global__ void __launch_bounds__(256) scan1_kernel(unsigned* __restrict__ cntA,
        unsigned* __restrict__ bucketTotal) {
    __shared__ unsigned sdata[256];
    int gb = blockIdx.x;
    int img = gb >> 8, lb = gb & (NBPI - 1);
    int t = threadIdx.x;
    const int PER = CHK / 256;   // 8 chunks per thread
    unsigned e[PER], s = 0;
    long base = ((long)img * CHK + (long)t * PER) * NBPI + lb;
    #pragma unroll
    for (int i = 0; i < PER; ++i) { e[i] = cntA[base + (long)i * NBPI]; s += e[i]; }
    unsigned mine = s;
    sdata[t] = s; __syncthreads();
    for (int off = 1; off < 256; off <<= 1) {
        unsigned v = (t >= off) ? sdata[t - off] : 0u; __syncthreads();
        sdata[t] += v; __syncthreads();
    }
    unsigned pre = sdata[t] - mine;   // exclusive prefix for this thread's chunks
    #pragma unroll
    for (int i = 0; i < PER; ++i) { unsigned cv = e[i]; cntA[base + (long)i * NBPI] = pre; pre += cv; }
    if (t == 255) bucketTotal[gb] = sdata[255];
}

// ---- pass 2b: exclusive scan over bucket totals --------------------------
__global__ void __launch_bounds__(NBG) scan2_kernel(const unsigned* __restrict__ bucketTotal,
        unsigned* __restrict__ bucketBase) {
    __shared__ unsigned sdata[NBG];
    int t = threadIdx.x;
    unsigned mine = bucketTotal[t];
    sdata[t] = mine; __syncthreads();
    for (int off = 1; off < NBG; off <<= 1) {
        unsigned v = (t >= off) ? sdata[t - off] : 0u; __syncthreads();
        sdata[t] += v; __syncthreads();
    }
    bucketBase[t] = sdata[t] - mine;
}

// ---- interp table: rank -> (feature slot, weight) ------------------------
__global__ void table_kernel(const unsigned* __restrict__ bucketTotal,
        int* __restrict__ tabK, float* __restrict__ tabW) {
    int t = threadIdx.x;
    for (int r = t; r < MAXPIX; r += 256) { tabK[r] = -1; tabW[r] = 0.f; }
    __syncthreads();
    if (t < NF) {
        int cnt = (int)(bucketTotal[0] / LPB);        // 1024 (equal partition)
        float Lf = (float)cnt;
        float p = ((float)t + 0.5f) * (Lf / (float)NF) - 0.5f;
        p = fminf(fmaxf(p, 0.0f), Lf - 1.0f);
        int i0 = (int)floorf(p);
        int i1 = min(i0 + 1, cnt - 1);
        float w = p - (float)i0;
        tabK[i0] = t; tabW[i0] = 1.0f - w;            // sample spacing 5.12 => no collisions
        tabK[i1] = t; tabW[i1] = w;
    }
}

// ---- pass 3: stable scatter into bucket regions (coalesced runs) ---------
__global__ void __launch_bounds__(256) scatterA_kernel(
        const float* __restrict__ img1, const float* __restrict__ img2,
        const float* __restrict__ flow1, const float* __restrict__ flow2,
        const int* __restrict__ mask1, const int* __restrict__ mask2,
        const unsigned* __restrict__ cntA, const unsigned* __restrict__ bucketBase,
        float* __restrict__ riv, float* __restrict__ rfz, unsigned char* __restrict__ rmeta) {
    __shared__ unsigned cur[4][NBPI];
    int w = threadIdx.x >> 6, lane = threadIdx.x & 63;
    int c = blockIdx.x * 4 + w;
    int img = c / CHK;
    const unsigned* cp = cntA + (long)c * NBPI;
    const unsigned* bp = bucketBase + img * NBPI;
    for (int j = lane; j < NBPI; j += 64) cur[w][j] = bp[j] + cp[j];  // wave-private
    const int*   mask  = img ? mask2  : mask1;
    const float* image = img ? img2   : img1;
    const float* flow  = img ? flow2  : flow1;
    long base = (long)(c - img*CHK) * PPC;
    for (int t = 0; t < PPC; t += 64) {
        long p = base + t + lane;
        int l = mask[p] - 1;
        float iv = image[p];
        float fx = flow[p], fy = flow[HW + p], fz = flow[2L*HW + p];
        int bkt = l >> 4;
        unsigned long long m = match_bits<8>(bkt);
        int cb = __popcll(m & ((1ull << lane) - 1ull));
        int ct = __popcll(m);
        unsigned r0 = cur[w][bkt];
        unsigned dst = r0 + (unsigned)cb;              // stable raster order in bucket
        if (cb == ct - 1) cur[w][bkt] = r0 + (unsigned)ct;
        int cx = fx < 0.f ? 0 : (fx == 0.f ? 1 : 2);
        int cy = fy < 0.f ? 0 : (fy == 0.f ? 1 : 2);
        riv[dst] = iv;
        rfz[dst] = fz;
        rmeta[dst] = (unsigned char)((l & 15) | ((cx * 3 + cy) << 4));
    }
}

// ---- pass 4: fused rank + features, one block per bucket -----------------
__global__ void __launch_bounds__(256) stageB_kernel(
        const float* __restrict__ riv, const float* __restrict__ rfz,
        const unsigned char* __restrict__ rmeta,
        const unsigned* __restrict__ bucketTotal, const unsigned* __restrict__ bucketBase,
        const int* __restrict__ tabK, const float* __restrict__ tabW,
        float* __restrict__ out, float* __restrict__ zfm) {
    __shared__ float acc[LPB * NF];          // 12.8 KB feature accumulators
    __shared__ float s_tw[MAXPIX];
    __shared__ int   s_tk[MAXPIX];
    __shared__ int   hist[LPB * 9];
    __shared__ float fzs[LPB];
    __shared__ int   qc[4][LPB];
    __shared__ int   cur[4][LPB];
    __shared__ int   lcnt[LPB];
    int t = threadIdx.x, w = t >> 6, lane = t & 63;
    int gb = blockIdx.x;
    for (int j = t; j < LPB*NF; j += 256) acc[j] = 0.f;
    for (int j = t; j < MAXPIX; j += 256) { s_tk[j] = tabK[j]; s_tw[j] = tabW[j]; }
    for (int j = t; j < LPB*9; j += 256) hist[j] = 0;
    if (t < LPB) fzs[t] = 0.f;
    for (int j = t; j < 4*LPB; j += 256) ((int*)qc)[j] = 0;
    __syncthreads();
    long base = (long)bucketBase[gb];
    int total = (int)bucketTotal[gb];
    int qsz = (total + 3) >> 2;
    int qbeg = w * qsz, qend = min(qbeg + qsz, total);
    int nit = (qend - qbeg + 63) >> 6;
    // phase 1: per-quarter per-label counts
    for (int it = 0; it < nit; ++it) {
        int i = qbeg + it*64 + lane;
        bool valid = i < qend;
        int meta = valid ? (int)rmeta[base + i] : 0;
        int ll = meta & 15;
        unsigned long long vm = __ballot(valid);
        unsigned long long m = match_bits<4>(ll) & vm;
        if (valid) {
            int cb = __popcll(m & ((1ull << lane) - 1ull));
            if (cb == 0) qc[w][ll] += __popcll(m);
        }
    }
    __syncthreads();
    if (t < LPB) {
        int s = 0;
        #pragma unroll
        for (int q = 0; q < 4; ++q) { cur[q][t] = s; s += qc[q][t]; }
        lcnt[t] = s;
    }
    __syncthreads();
    // phase 2: place (rank) + reduce
    for (int it = 0; it < nit; ++it) {
        int i = qbeg + it*64 + lane;
        bool valid = i < qend;
        int meta = valid ? (int)rmeta[base + i] : 0;
        float iv = valid ? riv[base + i] : 0.f;
        float fz = valid ? rfz[base + i] : 0.f;
        int ll = meta & 15, bin = meta >> 4;
        unsigned long long vm = __ballot(valid);
        unsigned long long m = match_bits<4>(ll) & vm;
        if (valid) {
            int cb = __popcll(m & ((1ull << lane) - 1ull));
            int ct = __popcll(m);
            int r0 = cur[w][ll];
            int rank = r0 + cb;
            if (cb == ct - 1) cur[w][ll] = r0 + ct;
            atomicAdd(&fzs[ll], fz);
            atomicAdd(&hist[ll*9 + bin], 1);
            int k = s_tk[rank];
            if (k >= 0) atomicAdd(&acc[ll*NF + k], iv * s_tw[rank]);  // commutative-exact pair
        }
    }
    __syncthreads();
    if (t < LPB) zfm[gb*LPB + t] = fzs[t] / (float)lcnt[t];
    if (t < FEAT) {
        for (int r = 0; r < LPB; ++r) {
            long gl = (long)gb * LPB + r;
            out[gl * FEAT + t] = (t < NF) ? acc[r*NF + t] : (float)hist[r*9 + (t - NF)];
        }
    }
}

// ---- edges: top-2 nearest centers ----------------------------------------
__device__ __forceinline__ bool better(float d, int j, float d2, int j2) {
    return d < d2 || (d == d2 && j < j2);
}

__global__ void __launch_bounds__(256) edge_kernel(const float* __restrict__ bbox1,
                                                   const float* __restrict__ bbox2,
                                                   const float* __restrict__ zfm,
                                                   float* __restrict__ out) {
    int wave = threadIdx.x >> 6, lane = threadIdx.x & 63;
    int i = blockIdx.x * 4 + wave;
    float c1x = bbox1[i*4 + 0], c1y = bbox1[i*4 + 1];
    float d0 = INFINITY; int j0 = 0x7fffffff;
    float d1 = INFINITY; int j1 = 0x7fffffff;
    for (int t = 0; t < NI; t += 64) {
        int j = t + lane;
        float dx = c1x - bbox2[j*4 + 0];
        float dy = c1y - bbox2[j*4 + 1];
        float dsq = dx*dx + dy*dy;                 // no fma (contract off)
        float d = (float)sqrt((double)dsq);        // correctly-rounded f32 sqrt
        if (better(d, j, d0, j0)) { d1 = d0; j1 = j0; d0 = d; j0 = j; }
        else if (better(d, j, d1, j1)) { d1 = d; j1 = j; }
    }
    for (int off = 32; off; off >>= 1) {
        float od0 = __shfl_down(d0, off); int oj0 = __shfl_down(j0, off);
        float od1 = __shfl_down(d1, off); int oj1 = __shfl_down(j1, off);
        if (better(od0, oj0, d0, j0)) {
            if (better(d0, j0, od1, oj1)) { d1 = d0; j1 = j0; }
            else                          { d1 = od1; j1 = oj1; }
            d0 = od0; j0 = oj0;
        } else if (better(od0, oj0, d1, j1)) { d1 = od0; j1 = oj0; }
    }
    if (lane == 0) {
        float z1 = zfm[i];
        int js[2] = { j0, j1 };
        for (int t = 0; t < 2; ++t) {
            int e = i*2 + t, j = js[t];
            out[EIOFF + e]      = (float)i;
            out[EIOFF + NE + e] = (float)(j + NI);
            float* ea = out + EAOFF + (long)e * 6;
            ea[0] = z1;
            ea[1] = zfm[NI + j];
            ea[2] = c1x - bbox2[j*4 + 0];
            ea[3] = c1y - bbox2[j*4 + 1];
            ea[4] = bbox1[i*4 + 2] / bbox2[j*4 + 2];
            ea[5] = bbox1[i*4 + 3] / bbox2[j*4 + 3];
        }
    }
}

extern "C" void kernel_launch(void* const* d_in, const int* in_sizes, int n_in,
                              void* d_out, int out_size, void* d_ws, size_t ws_size,
                              hipStream_t stream) {
    const float* img1  = (const float*)d_in[0];
    const float* img2  = (const float*)d_in[1];
    const float* flow1 = (const float*)d_in[2];
    const float* flow2 = (const float*)d_in[3];
    const float* bbox1 = (const float*)d_in[4];
    const float* bbox2 = (const float*)d_in[5];
    const int*   mask1 = (const int*)d_in[6];
    const int*   mask2 = (const int*)d_in[7];
    float* out = (float*)d_out;

    char* ws = (char*)d_ws;
    size_t off = 0;
    unsigned* cntA        = (unsigned*)(ws + off); off += (size_t)TOTCHK * NBPI * 4;  // 4 MB
    unsigned* bucketTotal = (unsigned*)(ws + off); off += NBG * 4;
    unsigned* bucketBase  = (unsigned*)(ws + off); off += NBG * 4;
    int*      tabK        = (int*)(ws + off);      off += MAXPIX * 4;
    float*    tabW        = (float*)(ws + off);    off += MAXPIX * 4;
    float*    riv         = (float*)(ws + off);    off += (size_t)REC * 4;            // 33.5 MB
    float*    rfz         = (float*)(ws + off);    off += (size_t)REC * 4;            // 33.5 MB
    float*    zfm         = (float*)(ws + off);    off += 2 * NI * 4;
    unsigned char* rmeta  = (unsigned char*)(ws + off); off += (size_t)REC;           // 8.4 MB

    hipLaunchKernelGGL(countA_kernel, dim3(TOTCHK/4), dim3(256), 0, stream, mask1, mask2, cntA);
    hipLaunchKernelGGL(scan1_kernel, dim3(NBG), dim3(256), 0, stream, cntA, bucketTotal);
    hipLaunchKernelGGL(scan2_kernel, dim3(1), dim3(NBG), 0, stream, bucketTotal, bucketBase);
    hipLaunchKernelGGL(table_kernel, dim3(1), dim3(256), 0, stream, bucketTotal, tabK, tabW);
    hipLaunchKernelGGL(scatterA_kernel, dim3(TOTCHK/4), dim3(256), 0, stream,
                       img1, img2, flow1, flow2, mask1, mask2, cntA, bucketBase,
                       riv, rfz, rmeta);
    hipLaunchKernelGGL(stageB_kernel, dim3(NBG), dim3(256), 0, stream,
                       riv, rfz, rmeta, bucketTotal, bucketBase, tabK, tabW, out, zfm);
    hipLaunchKernelGGL(edge_kernel, dim3(NI/4), dim3(256), 0, stream, bbox1, bbox2, zfm, out);
}

// Round 4
// 440.449 us; speedup vs baseline: 1.8801x; 1.8801x over previous
//
#include <hip/hip_runtime.h>
#include <math.h>

#pragma clang fp contract(off)

#define HW      (2048*2048)
#define NI      4096        // instances per image
#define MAXPIX  1024        // pixels per instance (equal partition)
#define NF      200
#define FEAT    209
#define NE      (NI*2)
#define XSIZE   ((2*NI)*FEAT)
#define EIOFF   XSIZE
#define EAOFF   (EIOFF + 2*NE)

#define S       4096        // pixels per chunk (one block)
#define CHK     (HW/S)      // 1024 chunks per image
#define TOTCHK  (2*CHK)     // 2048
#define NBPI    256         // buckets per image (16 labels each)
#define LPB     16
#define NBG     (2*NBPI)    // 512 global buckets
#define REC     (2*HW)

template<int NB>
__device__ __forceinline__ unsigned long long match_bits(int v) {
    unsigned long long m = ~0ull;
    #pragma unroll
    for (int bit = 0; bit < NB; ++bit) {
        unsigned long long bb = __ballot((v >> bit) & 1);
        m &= ((v >> bit) & 1) ? bb : ~bb;
    }
    return m;
}

// ---- pass 1: per-chunk per-bucket counts ---------------------------------
__global__ void __launch_bounds__(256) countA_kernel(const int* __restrict__ mask1,
        const int* __restrict__ mask2, unsigned* __restrict__ cntA) {
    __shared__ unsigned cnt[4][NBPI];
    int w = threadIdx.x >> 6, lane = threadIdx.x & 63;
    for (int j = threadIdx.x; j < 4*NBPI; j += 256) ((unsigned*)cnt)[j] = 0u;
    __syncthreads();
    int c = blockIdx.x * 4 + w;                 // global chunk id
    int img = c / CHK;
    const int* mask = img ? mask2 : mask1;
    long base = (long)(c - img*CHK) * S;
    for (int t = 0; t < S; t += 64) {
        int l = mask[base + t + lane] - 1;
        int bkt = l >> 4;
        unsigned long long m = match_bits<8>(bkt);
        int cb = __popcll(m & ((1ull << lane) - 1ull));
        if (cb == 0) cnt[w][bkt] += (unsigned)__popcll(m);
    }
    unsigned* dst = cntA + (long)c * NBPI;
    for (int j = lane; j < NBPI; j += 64) dst[j] = cnt[w][j];
}

// ---- pass 2a: per-bucket exclusive scan over its chunks ------------------
__global__ void __launch_bounds__(256) scan1_kernel(unsigned* __restrict__ cntA,
        unsigned* __restrict__ bucketTotal) {
    __shared__ unsigned sdata[256];
    int gb = blockIdx.x;
    int img = gb >> 8, lb = gb & (NBPI - 1);
    int t = threadIdx.x;
    const int PER = CHK / 256;   // 4 chunks per thread
    unsigned e[PER], s = 0;
    long base = ((long)img * CHK + (long)t * PER) * NBPI + lb;
    #pragma unroll
    for (int i = 0; i < PER; ++i) { e[i] = cntA[base + (long)i * NBPI]; s += e[i]; }
    unsigned mine = s;
    sdata[t] = s; __syncthreads();
    for (int off = 1; off < 256; off <<= 1) {
        unsigned v = (t >= off) ? sdata[t - off] : 0u; __syncthreads();
        sdata[t] += v; __syncthreads();
    }
    unsigned pre = sdata[t] - mine;
    #pragma unroll
    for (int i = 0; i < PER; ++i) { unsigned cv = e[i]; cntA[base + (long)i * NBPI] = pre; pre += cv; }
    if (t == 255) bucketTotal[gb] = sdata[255];
}

// ---- pass 2b: exclusive scan over bucket totals --------------------------
__global__ void __launch_bounds__(NBG) scan2_kernel(const unsigned* __restrict__ bucketTotal,
        unsigned* __restrict__ bucketBase) {
    __shared__ unsigned sdata[NBG];
    int t = threadIdx.x;
    unsigned mine = bucketTotal[t];
    sdata[t] = mine; __syncthreads();
    for (int off = 1; off < NBG; off <<= 1) {
        unsigned v = (t >= off) ? sdata[t - off] : 0u; __syncthreads();
        sdata[t] += v; __syncthreads();
    }
    bucketBase[t] = sdata[t] - mine;
}

// ---- interp table: rank -> (feature slot, weight) ------------------------
__global__ void table_kernel(const unsigned* __restrict__ bucketTotal,
        int* __restrict__ tabK, float* __restrict__ tabW) {
    int t = threadIdx.x;
    for (int r = t; r < MAXPIX; r += 256) { tabK[r] = -1; tabW[r] = 0.f; }
    __syncthreads();
    if (t < NF) {
        int cnt = (int)(bucketTotal[0] / LPB);        // 1024 (equal partition)
        float Lf = (float)cnt;
        float p = ((float)t + 0.5f) * (Lf / (float)NF) - 0.5f;
        p = fminf(fmaxf(p, 0.0f), Lf - 1.0f);
        int i0 = (int)floorf(p);
        int i1 = min(i0 + 1, cnt - 1);
        float w = p - (float)i0;
        tabK[i0] = t; tabW[i0] = 1.0f - w;            // spacing 5.12 => no collision
        tabK[i1] = t; tabW[i1] = w;
    }
}

// ---- pass 3: LDS-staged stable bucket sort, coalesced flush --------------
__global__ void __launch_bounds__(256) sort_kernel(
        const float* __restrict__ img1, const float* __restrict__ img2,
        const float* __restrict__ flow1, const float* __restrict__ flow2,
        const int* __restrict__ mask1, const int* __restrict__ mask2,
        const unsigned* __restrict__ cntA, const unsigned* __restrict__ bucketBase,
        float* __restrict__ riv, float* __restrict__ rfz, unsigned char* __restrict__ rmeta) {
    __shared__ float ivs[S];                 // 16 KB
    __shared__ float fzv[S];                 // 16 KB
    __shared__ unsigned char smeta[S];       // 4 KB
    __shared__ unsigned char sbkt[S];        // 4 KB
    __shared__ int qcnt[4][NBPI];            // 4 KB
    __shared__ int curw[4][NBPI];            // 4 KB
    __shared__ int sscan[NBPI];              // 1 KB
    __shared__ int gofs[NBPI];               // 1 KB
    int t = threadIdx.x, w = t >> 6, lane = t & 63;
    int c = blockIdx.x;                      // one chunk per block
    int img = c / CHK;
    const int*   mask  = img ? mask2  : mask1;
    const float* image = img ? img2   : img1;
    const float* flow  = img ? flow2  : flow1;
    long base = (long)(c - img*CHK) * S;
    for (int j = t; j < 4*NBPI; j += 256) ((int*)qcnt)[j] = 0;
    __syncthreads();
    // phase 1: per-wave per-bucket counts over this wave's quarter (raster order)
    long qbase = base + (long)w * (S/4);
    for (int it = 0; it < S/4; it += 64) {
        int l = mask[qbase + it + lane] - 1;
        int bkt = l >> 4;
        unsigned long long m = match_bits<8>(bkt);
        int cb = __popcll(m & ((1ull << lane) - 1ull));
        if (cb == 0) qcnt[w][bkt] += __popcll(m);
    }
    __syncthreads();
    // block scan over 256 buckets (t == bucket id)
    {
        int b = t;
        int tot = qcnt[0][b] + qcnt[1][b] + qcnt[2][b] + qcnt[3][b];
        sscan[b] = tot; __syncthreads();
        for (int off = 1; off < NBPI; off <<= 1) {
            int v = (b >= off) ? sscan[b - off] : 0; __syncthreads();
            sscan[b] += v; __syncthreads();
        }
        int excl = sscan[b] - tot;           // chunk-local bucket offset
        int run = excl;
        #pragma unroll
        for (int q = 0; q < 4; ++q) { curw[q][b] = run; run += qcnt[q][b]; }
        gofs[b] = (int)(bucketBase[img*NBPI + b] + cntA[(long)c * NBPI + b]) - excl;
    }
    __syncthreads();
    // phase 2: place records into LDS in bucket-major stable order
    for (int it = 0; it < S/4; it += 64) {
        long p = qbase + it + lane;
        int l = mask[p] - 1;
        float iv = image[p];
        float fx = flow[p], fy = flow[HW + p], fz = flow[2L*HW + p];
        int bkt = l >> 4;
        unsigned long long m = match_bits<8>(bkt);
        int cb = __popcll(m & ((1ull << lane) - 1ull));
        int ct = __popcll(m);
        int r0 = curw[w][bkt];
        int dst = r0 + cb;
        if (cb == ct - 1) curw[w][bkt] = r0 + ct;
        int cx = fx < 0.f ? 0 : (fx == 0.f ? 1 : 2);
        int cy = fy < 0.f ? 0 : (fy == 0.f ? 1 : 2);
        ivs[dst] = iv;
        fzv[dst] = fz;
        smeta[dst] = (unsigned char)((l & 15) | ((cx * 3 + cy) << 4));
        sbkt[dst] = (unsigned char)bkt;
    }
    __syncthreads();
    // phase 3: linear flush — consecutive j => consecutive global addresses per run
    for (int j = t; j < S; j += 256) {
        int b = sbkt[j];
        int g = gofs[b] + j;
        riv[g]   = ivs[j];
        rfz[g]   = fzv[j];
        rmeta[g] = smeta[j];
    }
}

// ---- pass 4: fused rank + features, one block per bucket (8 segments) ----
__global__ void __launch_bounds__(512) stageB_kernel(
        const float* __restrict__ riv, const float* __restrict__ rfz,
        const unsigned char* __restrict__ rmeta,
        const unsigned* __restrict__ bucketTotal, const unsigned* __restrict__ bucketBase,
        const int* __restrict__ tabK, const float* __restrict__ tabW,
        float* __restrict__ out, float* __restrict__ zfm) {
    __shared__ float acc[LPB * NF];          // 12.8 KB
    __shared__ float s_tw[MAXPIX];
    __shared__ int   s_tk[MAXPIX];
    __shared__ int   hist[LPB * 9];
    __shared__ float fzs[LPB];
    __shared__ int   qc[8][LPB];
    __shared__ int   cur[8][LPB];
    __shared__ int   lcnt[LPB];
    int t = threadIdx.x, w = t >> 6, lane = t & 63;
    int gb = blockIdx.x;
    for (int j = t; j < LPB*NF; j += 512) acc[j] = 0.f;
    for (int j = t; j < MAXPIX; j += 512) { s_tk[j] = tabK[j]; s_tw[j] = tabW[j]; }
    for (int j = t; j < LPB*9; j += 512) hist[j] = 0;
    if (t < LPB) fzs[t] = 0.f;
    for (int j = t; j < 8*LPB; j += 512) ((int*)qc)[j] = 0;
    __syncthreads();
    long base = (long)bucketBase[gb];
    int total = (int)bucketTotal[gb];
    int qsz = (total + 7) >> 3;
    int qbeg = w * qsz, qend = min(qbeg + qsz, total);
    int nit = (qend - qbeg + 63) >> 6;
    // phase 1: per-segment per-label counts
    for (int it = 0; it < nit; ++it) {
        int i = qbeg + it*64 + lane;
        bool valid = i < qend;
        int meta = valid ? (int)rmeta[base + i] : 0;
        int ll = meta & 15;
        unsigned long long vm = __ballot(valid);
        unsigned long long m = match_bits<4>(ll) & vm;
        if (valid) {
            int cb = __popcll(m & ((1ull << lane) - 1ull));
            if (cb == 0) qc[w][ll] += __popcll(m);
        }
    }
    __syncthreads();
    if (t < LPB) {
        int s = 0;
        #pragma unroll
        for (int q = 0; q < 8; ++q) { cur[q][t] = s; s += qc[q][t]; }
        lcnt[t] = s;
    }
    __syncthreads();
    // phase 2: rank + reduce
    for (int it = 0; it < nit; ++it) {
        int i = qbeg + it*64 + lane;
        bool valid = i < qend;
        int meta = valid ? (int)rmeta[base + i] : 0;
        float iv = valid ? riv[base + i] : 0.f;
        float fz = valid ? rfz[base + i] : 0.f;
        int ll = meta & 15, bin = meta >> 4;
        unsigned long long vm = __ballot(valid);
        unsigned long long m = match_bits<4>(ll) & vm;
        if (valid) {
            int cb = __popcll(m & ((1ull << lane) - 1ull));
            int ct = __popcll(m);
            int r0 = cur[w][ll];
            int rank = r0 + cb;
            if (cb == ct - 1) cur[w][ll] = r0 + ct;
            atomicAdd(&fzs[ll], fz);
            atomicAdd(&hist[ll*9 + bin], 1);
            int k = s_tk[rank];
            if (k >= 0) atomicAdd(&acc[ll*NF + k], iv * s_tw[rank]);  // commutative-exact pair
        }
    }
    __syncthreads();
    if (t < LPB) zfm[gb*LPB + t] = fzs[t] / (float)lcnt[t];
    if (t < FEAT) {
        for (int r = 0; r < LPB; ++r) {
            long gl = (long)gb * LPB + r;
            out[gl * FEAT + t] = (t < NF) ? acc[r*NF + t] : (float)hist[r*9 + (t - NF)];
        }
    }
}

// ---- edges: top-2 nearest centers ----------------------------------------
__device__ __forceinline__ bool better(float d, int j, float d2, int j2) {
    return d < d2 || (d == d2 && j < j2);
}

__global__ void __launch_bounds__(256) edge_kernel(const float* __restrict__ bbox1,
                                                   const float* __restrict__ bbox2,
                                                   const float* __restrict__ zfm,
                                                   float* __restrict__ out) {
    int wave = threadIdx.x >> 6, lane = threadIdx.x & 63;
    int i = blockIdx.x * 4 + wave;
    float c1x = bbox1[i*4 + 0], c1y = bbox1[i*4 + 1];
    float d0 = INFINITY; int j0 = 0x7fffffff;
    float d1 = INFINITY; int j1 = 0x7fffffff;
    for (int t = 0; t < NI; t += 64) {
        int j = t + lane;
        float dx = c1x - bbox2[j*4 + 0];
        float dy = c1y - bbox2[j*4 + 1];
        float dsq = dx*dx + dy*dy;                 // no fma (contract off)
        float d = (float)sqrt((double)dsq);        // correctly-rounded f32 sqrt
        if (better(d, j, d0, j0)) { d1 = d0; j1 = j0; d0 = d; j0 = j; }
        else if (better(d, j, d1, j1)) { d1 = d; j1 = j; }
    }
    for (int off = 32; off; off >>= 1) {
        float od0 = __shfl_down(d0, off); int oj0 = __shfl_down(j0, off);
        float od1 = __shfl_down(d1, off); int oj1 = __shfl_down(j1, off);
        if (better(od0, oj0, d0, j0)) {
            if (better(d0, j0, od1, oj1)) { d1 = d0; j1 = j0; }
            else                          { d1 = od1; j1 = oj1; }
            d0 = od0; j0 = oj0;
        } else if (better(od0, oj0, d1, j1)) { d1 = od0; j1 = oj0; }
    }
    if (lane == 0) {
        float z1 = zfm[i];
        int js[2] = { j0, j1 };
        for (int t = 0; t < 2; ++t) {
            int e = i*2 + t, j = js[t];
            out[EIOFF + e]      = (float)i;
            out[EIOFF + NE + e] = (float)(j + NI);
            float* ea = out + EAOFF + (long)e * 6;
            ea[0] = z1;
            ea[1] = zfm[NI + j];
            ea[2] = c1x - bbox2[j*4 + 0];
            ea[3] = c1y - bbox2[j*4 + 1];
            ea[4] = bbox1[i*4 + 2] / bbox2[j*4 + 2];
            ea[5] = bbox1[i*4 + 3] / bbox2[j*4 + 3];
        }
    }
}

extern "C" void kernel_launch(void* const* d_in, const int* in_sizes, int n_in,
                              void* d_out, int out_size, void* d_ws, size_t ws_size,
                              hipStream_t stream) {
    const float* img1  = (const float*)d_in[0];
    const float* img2  = (const float*)d_in[1];
    const float* flow1 = (const float*)d_in[2];
    const float* flow2 = (const float*)d_in[3];
    const float* bbox1 = (const float*)d_in[4];
    const float* bbox2 = (const float*)d_in[5];
    const int*   mask1 = (const int*)d_in[6];
    const int*   mask2 = (const int*)d_in[7];
    float* out = (float*)d_out;

    char* ws = (char*)d_ws;
    size_t off = 0;
    unsigned* cntA        = (unsigned*)(ws + off); off += (size_t)TOTCHK * NBPI * 4;  // 2 MB
    unsigned* bucketTotal = (unsigned*)(ws + off); off += NBG * 4;
    unsigned* bucketBase  = (unsigned*)(ws + off); off += NBG * 4;
    int*      tabK        = (int*)(ws + off);      off += MAXPIX * 4;
    float*    tabW        = (float*)(ws + off);    off += MAXPIX * 4;
    float*    riv         = (float*)(ws + off);    off += (size_t)REC * 4;            // 33.5 MB
    float*    rfz         = (float*)(ws + off);    off += (size_t)REC * 4;            // 33.5 MB
    float*    zfm         = (float*)(ws + off);    off += 2 * NI * 4;
    unsigned char* rmeta  = (unsigned char*)(ws + off); off += (size_t)REC;           // 8.4 MB

    hipLaunchKernelGGL(countA_kernel, dim3(TOTCHK/4), dim3(256), 0, stream, mask1, mask2, cntA);
    hipLaunchKernelGGL(scan1_kernel, dim3(NBG), dim3(256), 0, stream, cntA, bucketTotal);
    hipLaunchKernelGGL(scan2_kernel, dim3(1), dim3(NBG), 0, stream, bucketTotal, bucketBase);
    hipLaunchKernelGGL(table_kernel, dim3(1), dim3(256), 0, stream, bucketTotal, tabK, tabW);
    hipLaunchKernelGGL(sort_kernel, dim3(TOTCHK), dim3(256), 0, stream,
                       img1, img2, flow1, flow2, mask1, mask2, cntA, bucketBase,
                       riv, rfz, rmeta);
    hipLaunchKernelGGL(stageB_kernel, dim3(NBG), dim3(512), 0, stream,
                       riv, rfz, rmeta, bucketTotal, bucketBase, tabK, tabW, out, zfm);
    hipLaunchKernelGGL(edge_kernel, dim3(NI/4), dim3(256), 0, stream, bbox1, bbox2, zfm, out);
}

// Round 5
// 389.763 us; speedup vs baseline: 2.1246x; 1.1300x over previous
//
#include <hip/hip_runtime.h>
#include <math.h>

#pragma clang fp contract(off)

#define HW      (2048*2048)
#define NI      4096        // instances per image
#define MAXPIX  1024        // pixels per instance (equal partition)
#define NF      200
#define FEAT    209
#define NE      (NI*2)
#define XSIZE   ((2*NI)*FEAT)
#define EIOFF   XSIZE
#define EAOFF   (EIOFF + 2*NE)

#define S       4096        // pixels per chunk (one sort block)
#define CHK     (HW/S)      // 1024 chunks per image
#define TOTCHK  (2*CHK)     // 2048
#define NBPI    256         // buckets per image (16 labels each)
#define LPB     16
#define NBG     (2*NBPI)    // 512 global buckets
#define REC     (2*HW)

template<int NB>
__device__ __forceinline__ unsigned long long match_bits(int v) {
    unsigned long long m = ~0ull;
    #pragma unroll
    for (int bit = 0; bit < NB; ++bit) {
        unsigned long long bb = __ballot((v >> bit) & 1);
        m &= ((v >> bit) & 1) ? bb : ~bb;
    }
    return m;
}

// ---- pass 1: per-chunk per-bucket counts (LDS atomics, streaming) --------
__global__ void __launch_bounds__(256) countA_kernel(const int* __restrict__ mask1,
        const int* __restrict__ mask2, unsigned* __restrict__ cntA) {
    __shared__ unsigned cnt[4][NBPI];
    int w = threadIdx.x >> 6, lane = threadIdx.x & 63;
    for (int j = threadIdx.x; j < 4*NBPI; j += 256) ((unsigned*)cnt)[j] = 0u;
    __syncthreads();
    int c = blockIdx.x * 4 + w;                 // global chunk id (per-wave chunk)
    int img = c / CHK;
    const int* mask = img ? mask2 : mask1;
    long base = (long)(c - img*CHK) * S;
    for (int t = 0; t < S; t += 64) {
        int l = mask[base + t + lane] - 1;
        atomicAdd(&cnt[w][l >> 4], 1u);         // counting: order-free
    }
    __syncthreads();
    unsigned* dst = cntA + (long)c * NBPI;
    for (int j = lane; j < NBPI; j += 64) dst[j] = cnt[w][j];
}

// ---- pass 2a: per-bucket exclusive scan over its chunks ------------------
__global__ void __launch_bounds__(256) scan1_kernel(unsigned* __restrict__ cntA,
        unsigned* __restrict__ bucketTotal) {
    __shared__ unsigned sdata[256];
    int gb = blockIdx.x;
    int img = gb >> 8, lb = gb & (NBPI - 1);
    int t = threadIdx.x;
    const int PER = CHK / 256;   // 4 chunks per thread
    unsigned e[PER], s = 0;
    long base = ((long)img * CHK + (long)t * PER) * NBPI + lb;
    #pragma unroll
    for (int i = 0; i < PER; ++i) { e[i] = cntA[base + (long)i * NBPI]; s += e[i]; }
    unsigned mine = s;
    sdata[t] = s; __syncthreads();
    for (int off = 1; off < 256; off <<= 1) {
        unsigned v = (t >= off) ? sdata[t - off] : 0u; __syncthreads();
        sdata[t] += v; __syncthreads();
    }
    unsigned pre = sdata[t] - mine;
    #pragma unroll
    for (int i = 0; i < PER; ++i) { unsigned cv = e[i]; cntA[base + (long)i * NBPI] = pre; pre += cv; }
    if (t == 255) bucketTotal[gb] = sdata[255];
}

// ---- pass 2b: exclusive scan over bucket totals --------------------------
__global__ void __launch_bounds__(NBG) scan2_kernel(const unsigned* __restrict__ bucketTotal,
        unsigned* __restrict__ bucketBase) {
    __shared__ unsigned sdata[NBG];
    int t = threadIdx.x;
    unsigned mine = bucketTotal[t];
    sdata[t] = mine; __syncthreads();
    for (int off = 1; off < NBG; off <<= 1) {
        unsigned v = (t >= off) ? sdata[t - off] : 0u; __syncthreads();
        sdata[t] += v; __syncthreads();
    }
    bucketBase[t] = sdata[t] - mine;
}

// ---- interp table: rank -> (feature slot, weight) ------------------------
__global__ void table_kernel(const unsigned* __restrict__ bucketTotal,
        int* __restrict__ tabK, float* __restrict__ tabW) {
    int t = threadIdx.x;
    for (int r = t; r < MAXPIX; r += 256) { tabK[r] = -1; tabW[r] = 0.f; }
    __syncthreads();
    if (t < NF) {
        int cnt = (int)(bucketTotal[0] / LPB);        // 1024 (equal partition)
        float Lf = (float)cnt;
        float p = ((float)t + 0.5f) * (Lf / (float)NF) - 0.5f;
        p = fminf(fmaxf(p, 0.0f), Lf - 1.0f);
        int i0 = (int)floorf(p);
        int i1 = min(i0 + 1, cnt - 1);
        float w = p - (float)i0;
        tabK[i0] = t; tabW[i0] = 1.0f - w;            // spacing 5.12 => no collision
        tabK[i1] = t; tabW[i1] = w;
    }
}

// ---- pass 3: LDS-staged stable bucket sort, 512 thr, single-ballot -------
__global__ void __launch_bounds__(512) sort_kernel(
        const float* __restrict__ img1, const float* __restrict__ img2,
        const float* __restrict__ flow1, const float* __restrict__ flow2,
        const int* __restrict__ mask1, const int* __restrict__ mask2,
        const unsigned* __restrict__ cntA, const unsigned* __restrict__ bucketBase,
        float* __restrict__ riv, float* __restrict__ rfz, unsigned char* __restrict__ rmeta) {
    __shared__ float ivs[S];                     // 16 KB
    __shared__ float fzv[S];                     // 16 KB
    __shared__ unsigned short smeta[S];          // 8 KB  (bkt<<8 | bin<<4 | ll)
    __shared__ unsigned short qcnt[8][NBPI];     // 4 KB
    __shared__ unsigned short curw[8][NBPI];     // 4 KB
    __shared__ unsigned short sscan[NBPI];       // 0.5 KB
    __shared__ int gofs[NBPI];                   // 1 KB   => ~50.7 KB total
    int t = threadIdx.x, w = t >> 6, lane = t & 63;
    int c = blockIdx.x;
    int img = c / CHK;
    const int*   mask  = img ? mask2  : mask1;
    const float* image = img ? img2   : img1;
    const float* flow  = img ? flow2  : flow1;
    long base = (long)(c - img*CHK) * S;
    for (int j = t; j < 8*NBPI; j += 512) ((unsigned short*)qcnt)[j] = 0;
    __syncthreads();
    // phase 1: per-wave-segment bucket counts; cache ballot mask + label in regs
    long qbase = base + (long)w * (S/8);
    unsigned long long mreg[8];
    int lreg[8];
    unsigned long long ltmask = (1ull << lane) - 1ull;
    #pragma unroll
    for (int it = 0; it < 8; ++it) {
        int l = mask[qbase + it*64 + lane] - 1;
        int bkt = l >> 4;
        unsigned long long m = match_bits<8>(bkt);
        mreg[it] = m; lreg[it] = l;
        int cb = __popcll(m & ltmask);
        if (cb == 0) qcnt[w][bkt] += (unsigned short)__popcll(m);  // leaders: distinct addrs
    }
    __syncthreads();
    // block scan over 256 buckets (threads 0..255)
    {
        int tot = 0;
        if (t < NBPI) {
            #pragma unroll
            for (int q = 0; q < 8; ++q) tot += qcnt[q][t];
            sscan[t] = (unsigned short)tot;
        }
        __syncthreads();
        for (int off = 1; off < NBPI; off <<= 1) {
            int v = 0;
            if (t < NBPI && t >= off) v = sscan[t - off];
            __syncthreads();
            if (t < NBPI) sscan[t] = (unsigned short)(sscan[t] + v);
            __syncthreads();
        }
        if (t < NBPI) {
            int excl = (int)sscan[t] - tot;      // chunk-local bucket offset
            int run = excl;
            #pragma unroll
            for (int q = 0; q < 8; ++q) { curw[q][t] = (unsigned short)run; run += qcnt[q][t]; }
            gofs[t] = (int)(bucketBase[img*NBPI + t] + cntA[(long)c * NBPI + t]) - excl;
        }
    }
    __syncthreads();
    // phase 2: place records into LDS (reuse cached masks — no re-ballot)
    #pragma unroll
    for (int it = 0; it < 8; ++it) {
        long p = qbase + it*64 + lane;
        float iv = image[p];
        float fx = flow[p], fy = flow[HW + p], fz = flow[2L*HW + p];
        unsigned long long m = mreg[it];
        int l = lreg[it], bkt = l >> 4;
        int cb = __popcll(m & ltmask);
        int ct = __popcll(m);
        int r0 = (int)curw[w][bkt];
        int dst = r0 + cb;
        if (cb == ct - 1) curw[w][bkt] = (unsigned short)(r0 + ct);
        int cx = fx < 0.f ? 0 : (fx == 0.f ? 1 : 2);
        int cy = fy < 0.f ? 0 : (fy == 0.f ? 1 : 2);
        ivs[dst] = iv;
        fzv[dst] = fz;
        smeta[dst] = (unsigned short)((bkt << 8) | ((cx * 3 + cy) << 4) | (l & 15));
    }
    __syncthreads();
    // phase 3: linear flush — consecutive j => contiguous global runs
    for (int j = t; j < S; j += 512) {
        int ms = (int)smeta[j];
        int b = ms >> 8;
        int g = gofs[b] + j;
        riv[g]   = ivs[j];
        rfz[g]   = fzv[j];
        rmeta[g] = (unsigned char)(ms & 0xFF);
    }
}

// ---- pass 4: fused rank + features, one block per bucket (8 segments) ----
__global__ void __launch_bounds__(512) stageB_kernel(
        const float* __restrict__ riv, const float* __restrict__ rfz,
        const unsigned char* __restrict__ rmeta,
        const unsigned* __restrict__ bucketTotal, const unsigned* __restrict__ bucketBase,
        const int* __restrict__ tabK, const float* __restrict__ tabW,
        float* __restrict__ out, float* __restrict__ zfm) {
    __shared__ float acc[LPB * NF];          // 12.8 KB
    __shared__ float s_tw[MAXPIX];
    __shared__ int   s_tk[MAXPIX];
    __shared__ int   hist[LPB * 9];
    __shared__ float fzs[LPB];
    __shared__ unsigned qc[8][LPB];
    __shared__ int   cur[8][LPB];
    __shared__ int   lcnt[LPB];
    int t = threadIdx.x, w = t >> 6, lane = t & 63;
    int gb = blockIdx.x;
    for (int j = t; j < LPB*NF; j += 512) acc[j] = 0.f;
    for (int j = t; j < MAXPIX; j += 512) { s_tk[j] = tabK[j]; s_tw[j] = tabW[j]; }
    for (int j = t; j < LPB*9; j += 512) hist[j] = 0;
    if (t < LPB) fzs[t] = 0.f;
    for (int j = t; j < 8*LPB; j += 512) ((unsigned*)qc)[j] = 0u;
    __syncthreads();
    long base = (long)bucketBase[gb];
    int total = (int)bucketTotal[gb];
    int qsz = (total + 7) >> 3;
    int qbeg = w * qsz, qend = min(qbeg + qsz, total);
    int nit = (qend - qbeg + 63) >> 6;
    // phase 1: per-segment per-label counts (LDS atomics — order-free)
    for (int it = 0; it < nit; ++it) {
        int i = qbeg + it*64 + lane;
        if (i < qend) atomicAdd(&qc[w][rmeta[base + i] & 15], 1u);
    }
    __syncthreads();
    if (t < LPB) {
        int s = 0;
        #pragma unroll
        for (int q = 0; q < 8; ++q) { cur[q][t] = s; s += (int)qc[q][t]; }
        lcnt[t] = s;
    }
    __syncthreads();
    // phase 2: stable rank + reduce
    for (int it = 0; it < nit; ++it) {
        int i = qbeg + it*64 + lane;
        bool valid = i < qend;
        int meta = valid ? (int)rmeta[base + i] : 0;
        float iv = valid ? riv[base + i] : 0.f;
        float fz = valid ? rfz[base + i] : 0.f;
        int ll = meta & 15, bin = meta >> 4;
        unsigned long long vm = __ballot(valid);
        unsigned long long m = match_bits<4>(ll) & vm;
        if (valid) {
            int cb = __popcll(m & ((1ull << lane) - 1ull));
            int ct = __popcll(m);
            int r0 = cur[w][ll];
            int rank = r0 + cb;
            if (cb == ct - 1) cur[w][ll] = r0 + ct;
            atomicAdd(&fzs[ll], fz);
            atomicAdd(&hist[ll*9 + bin], 1);
            int k = s_tk[rank];
            if (k >= 0) atomicAdd(&acc[ll*NF + k], iv * s_tw[rank]);  // commutative-exact pair
        }
    }
    __syncthreads();
    if (t < LPB) zfm[gb*LPB + t] = fzs[t] / (float)lcnt[t];
    if (t < FEAT) {
        for (int r = 0; r < LPB; ++r) {
            long gl = (long)gb * LPB + r;
            out[gl * FEAT + t] = (t < NF) ? acc[r*NF + t] : (float)hist[r*9 + (t - NF)];
        }
    }
}

// ---- edges: top-2 nearest centers ----------------------------------------
__device__ __forceinline__ bool better(float d, int j, float d2, int j2) {
    return d < d2 || (d == d2 && j < j2);
}

__global__ void __launch_bounds__(256) edge_kernel(const float* __restrict__ bbox1,
                                                   const float* __restrict__ bbox2,
                                                   const float* __restrict__ zfm,
                                                   float* __restrict__ out) {
    int wave = threadIdx.x >> 6, lane = threadIdx.x & 63;
    int i = blockIdx.x * 4 + wave;
    float c1x = bbox1[i*4 + 0], c1y = bbox1[i*4 + 1];
    float d0 = INFINITY; int j0 = 0x7fffffff;
    float d1 = INFINITY; int j1 = 0x7fffffff;
    for (int t = 0; t < NI; t += 64) {
        int j = t + lane;
        float dx = c1x - bbox2[j*4 + 0];
        float dy = c1y - bbox2[j*4 + 1];
        float dsq = dx*dx + dy*dy;                 // no fma (contract off)
        float d = (float)sqrt((double)dsq);        // correctly-rounded f32 sqrt
        if (better(d, j, d0, j0)) { d1 = d0; j1 = j0; d0 = d; j0 = j; }
        else if (better(d, j, d1, j1)) { d1 = d; j1 = j; }
    }
    for (int off = 32; off; off >>= 1) {
        float od0 = __shfl_down(d0, off); int oj0 = __shfl_down(j0, off);
        float od1 = __shfl_down(d1, off); int oj1 = __shfl_down(j1, off);
        if (better(od0, oj0, d0, j0)) {
            if (better(d0, j0, od1, oj1)) { d1 = d0; j1 = j0; }
            else                          { d1 = od1; j1 = oj1; }
            d0 = od0; j0 = oj0;
        } else if (better(od0, oj0, d1, j1)) { d1 = od0; j1 = oj0; }
    }
    if (lane == 0) {
        float z1 = zfm[i];
        int js[2] = { j0, j1 };
        for (int t = 0; t < 2; ++t) {
            int e = i*2 + t, j = js[t];
            out[EIOFF + e]      = (float)i;
            out[EIOFF + NE + e] = (float)(j + NI);
            float* ea = out + EAOFF + (long)e * 6;
            ea[0] = z1;
            ea[1] = zfm[NI + j];
            ea[2] = c1x - bbox2[j*4 + 0];
            ea[3] = c1y - bbox2[j*4 + 1];
            ea[4] = bbox1[i*4 + 2] / bbox2[j*4 + 2];
            ea[5] = bbox1[i*4 + 3] / bbox2[j*4 + 3];
        }
    }
}

extern "C" void kernel_launch(void* const* d_in, const int* in_sizes, int n_in,
                              void* d_out, int out_size, void* d_ws, size_t ws_size,
                              hipStream_t stream) {
    const float* img1  = (const float*)d_in[0];
    const float* img2  = (const float*)d_in[1];
    const float* flow1 = (const float*)d_in[2];
    const float* flow2 = (const float*)d_in[3];
    const float* bbox1 = (const float*)d_in[4];
    const float* bbox2 = (const float*)d_in[5];
    const int*   mask1 = (const int*)d_in[6];
    const int*   mask2 = (const int*)d_in[7];
    float* out = (float*)d_out;

    char* ws = (char*)d_ws;
    size_t off = 0;
    unsigned* cntA        = (unsigned*)(ws + off); off += (size_t)TOTCHK * NBPI * 4;  // 2 MB
    unsigned* bucketTotal = (unsigned*)(ws + off); off += NBG * 4;
    unsigned* bucketBase  = (unsigned*)(ws + off); off += NBG * 4;
    int*      tabK        = (int*)(ws + off);      off += MAXPIX * 4;
    float*    tabW        = (float*)(ws + off);    off += MAXPIX * 4;
    float*    riv         = (float*)(ws + off);    off += (size_t)REC * 4;            // 33.5 MB
    float*    rfz         = (float*)(ws + off);    off += (size_t)REC * 4;            // 33.5 MB
    float*    zfm         = (float*)(ws + off);    off += 2 * NI * 4;
    unsigned char* rmeta  = (unsigned char*)(ws + off); off += (size_t)REC;           // 8.4 MB

    hipLaunchKernelGGL(countA_kernel, dim3(TOTCHK/4), dim3(256), 0, stream, mask1, mask2, cntA);
    hipLaunchKernelGGL(scan1_kernel, dim3(NBG), dim3(256), 0, stream, cntA, bucketTotal);
    hipLaunchKernelGGL(scan2_kernel, dim3(1), dim3(NBG), 0, stream, bucketTotal, bucketBase);
    hipLaunchKernelGGL(table_kernel, dim3(1), dim3(256), 0, stream, bucketTotal, tabK, tabW);
    hipLaunchKernelGGL(sort_kernel, dim3(TOTCHK), dim3(512), 0, stream,
                       img1, img2, flow1, flow2, mask1, mask2, cntA, bucketBase,
                       riv, rfz, rmeta);
    hipLaunchKernelGGL(stageB_kernel, dim3(NBG), dim3(512), 0, stream,
                       riv, rfz, rmeta, bucketTotal, bucketBase, tabK, tabW, out, zfm);
    hipLaunchKernelGGL(edge_kernel, dim3(NI/4), dim3(256), 0, stream, bbox1, bbox2, zfm, out);
}

// Round 6
// 348.435 us; speedup vs baseline: 2.3766x; 1.1186x over previous
//
#include <hip/hip_runtime.h>
#include <math.h>

#pragma clang fp contract(off)

#define HW      (2048*2048)
#define NI      4096        // instances per image
#define MAXPIX  1024        // pixels per instance (equal partition)
#define NF      200
#define FEAT    209
#define NE      (NI*2)
#define XSIZE   ((2*NI)*FEAT)
#define EIOFF   XSIZE
#define EAOFF   (EIOFF + 2*NE)

#define S       4096        // pixels per chunk (one sort block)
#define CHK     (HW/S)      // 1024 chunks per image
#define TOTCHK  (2*CHK)     // 2048
#define NBPI    256         // buckets per image (16 labels each)
#define LPB     16
#define NBG     (2*NBPI)    // 512 global buckets
#define REC     (2*HW)
#define CBLK    (TOTCHK/4)  // count blocks (4 chunks each) = 512

template<int NB>
__device__ __forceinline__ unsigned long long match_bits(int v) {
    unsigned long long m = ~0ull;
    #pragma unroll
    for (int bit = 0; bit < NB; ++bit) {
        unsigned long long bb = __ballot((v >> bit) & 1);
        m &= ((v >> bit) & 1) ? bb : ~bb;
    }
    return m;
}

// ---- pass 1: per-chunk bucket counts + per-block per-label fz partials ---
__global__ void __launch_bounds__(256) count_zf_kernel(const int* __restrict__ mask1,
        const int* __restrict__ mask2, const float* __restrict__ flow1,
        const float* __restrict__ flow2, unsigned* __restrict__ cntA,
        float* __restrict__ zfpart) {
    __shared__ unsigned cnt[4][NBPI];    // 4 KB
    __shared__ float zfp[NI];            // 16 KB
    int w = threadIdx.x >> 6, lane = threadIdx.x & 63;
    for (int j = threadIdx.x; j < 4*NBPI; j += 256) ((unsigned*)cnt)[j] = 0u;
    for (int j = threadIdx.x; j < NI; j += 256) zfp[j] = 0.f;
    __syncthreads();
    int c = blockIdx.x * 4 + w;                 // per-wave chunk; all 4 same image
    int img = c / CHK;
    const int*   mask  = img ? mask2 : mask1;
    const float* flowz = (img ? flow2 : flow1) + 2L*HW;
    long base = (long)(c - img*CHK) * S;
    for (int t = 0; t < S; t += 64) {
        int l = mask[base + t + lane] - 1;
        float fz = flowz[base + t + lane];
        atomicAdd(&cnt[w][l >> 4], 1u);         // counting: order-free
        atomicAdd(&zfp[l], fz);                 // LDS f32 atomic, rare collisions
    }
    __syncthreads();
    unsigned* dst = cntA + (long)c * NBPI;
    for (int j = lane; j < NBPI; j += 64) dst[j] = cnt[w][j];
    float* zdst = zfpart + (long)blockIdx.x * NI;
    for (int j = threadIdx.x; j < NI; j += 256) zdst[j] = zfp[j];
}

// ---- pass 2a: per-bucket exclusive scan over its chunks ------------------
__global__ void __launch_bounds__(256) scan1_kernel(unsigned* __restrict__ cntA,
        unsigned* __restrict__ bucketTotal) {
    __shared__ unsigned sdata[256];
    int gb = blockIdx.x;
    int img = gb >> 8, lb = gb & (NBPI - 1);
    int t = threadIdx.x;
    const int PER = CHK / 256;   // 4 chunks per thread
    unsigned e[PER], s = 0;
    long base = ((long)img * CHK + (long)t * PER) * NBPI + lb;
    #pragma unroll
    for (int i = 0; i < PER; ++i) { e[i] = cntA[base + (long)i * NBPI]; s += e[i]; }
    unsigned mine = s;
    sdata[t] = s; __syncthreads();
    for (int off = 1; off < 256; off <<= 1) {
        unsigned v = (t >= off) ? sdata[t - off] : 0u; __syncthreads();
        sdata[t] += v; __syncthreads();
    }
    unsigned pre = sdata[t] - mine;
    #pragma unroll
    for (int i = 0; i < PER; ++i) { unsigned cv = e[i]; cntA[base + (long)i * NBPI] = pre; pre += cv; }
    if (t == 255) bucketTotal[gb] = sdata[255];
}

// ---- pass 2b: exclusive scan over bucket totals --------------------------
__global__ void __launch_bounds__(NBG) scan2_kernel(const unsigned* __restrict__ bucketTotal,
        unsigned* __restrict__ bucketBase) {
    __shared__ unsigned sdata[NBG];
    int t = threadIdx.x;
    unsigned mine = bucketTotal[t];
    sdata[t] = mine; __syncthreads();
    for (int off = 1; off < NBG; off <<= 1) {
        unsigned v = (t >= off) ? sdata[t - off] : 0u; __syncthreads();
        sdata[t] += v; __syncthreads();
    }
    bucketBase[t] = sdata[t] - mine;
}

// ---- interp table: rank -> (feature slot, weight) ------------------------
__global__ void table_kernel(const unsigned* __restrict__ bucketTotal,
        int* __restrict__ tabK, float* __restrict__ tabW) {
    int t = threadIdx.x;
    for (int r = t; r < MAXPIX; r += 256) { tabK[r] = -1; tabW[r] = 0.f; }
    __syncthreads();
    if (t < NF) {
        int cnt = (int)(bucketTotal[0] / LPB);        // 1024 (equal partition)
        float Lf = (float)cnt;
        float p = ((float)t + 0.5f) * (Lf / (float)NF) - 0.5f;
        p = fminf(fmaxf(p, 0.0f), Lf - 1.0f);
        int i0 = (int)floorf(p);
        int i1 = min(i0 + 1, cnt - 1);
        float w = p - (float)i0;
        tabK[i0] = t; tabW[i0] = 1.0f - w;            // spacing 5.12 => no collision
        tabK[i1] = t; tabW[i1] = w;
    }
}

// ---- pass 3: LDS-staged stable bucket sort (29.5 KB LDS, 100% occ) -------
__global__ void __launch_bounds__(512) sort_kernel(
        const float* __restrict__ img1, const float* __restrict__ img2,
        const float* __restrict__ flow1, const float* __restrict__ flow2,
        const int* __restrict__ mask1, const int* __restrict__ mask2,
        const unsigned* __restrict__ cntA, const unsigned* __restrict__ bucketBase,
        float* __restrict__ riv, unsigned char* __restrict__ rmeta) {
    __shared__ float ivs[S];                     // 16 KB
    __shared__ unsigned short smeta[S];          // 8 KB  (bkt<<8 | bin<<4 | ll)
    __shared__ unsigned short cw[8][NBPI];       // 4 KB  (counts, then cursors in place)
    __shared__ unsigned short sscan[NBPI];       // 0.5 KB
    __shared__ int gofs[NBPI];                   // 1 KB   => 29.5 KB total
    int t = threadIdx.x, w = t >> 6, lane = t & 63;
    int c = blockIdx.x;
    int img = c / CHK;
    const int*   mask  = img ? mask2  : mask1;
    const float* image = img ? img2   : img1;
    const float* flow  = img ? flow2  : flow1;
    long base = (long)(c - img*CHK) * S;
    for (int j = t; j < 8*NBPI; j += 512) ((unsigned short*)cw)[j] = 0;
    __syncthreads();
    // phase 1: per-wave-segment bucket counts; cache ballot mask + label in regs
    long qbase = base + (long)w * (S/8);
    unsigned long long mreg[8];
    int lreg[8];
    unsigned long long ltmask = (1ull << lane) - 1ull;
    #pragma unroll
    for (int it = 0; it < 8; ++it) {
        int l = mask[qbase + it*64 + lane] - 1;
        int bkt = l >> 4;
        unsigned long long m = match_bits<8>(bkt);
        mreg[it] = m; lreg[it] = l;
        int cb = __popcll(m & ltmask);
        if (cb == 0) cw[w][bkt] += (unsigned short)__popcll(m);  // leaders: distinct addrs
    }
    __syncthreads();
    // block scan over 256 buckets (threads 0..255); convert cw in place to cursors
    {
        int tot = 0;
        if (t < NBPI) {
            #pragma unroll
            for (int q = 0; q < 8; ++q) tot += cw[q][t];
            sscan[t] = (unsigned short)tot;
        }
        __syncthreads();
        for (int off = 1; off < NBPI; off <<= 1) {
            int v = 0;
            if (t < NBPI && t >= off) v = sscan[t - off];
            __syncthreads();
            if (t < NBPI) sscan[t] = (unsigned short)(sscan[t] + v);
            __syncthreads();
        }
        if (t < NBPI) {
            int excl = (int)sscan[t] - tot;      // chunk-local bucket offset
            int run = excl;
            #pragma unroll
            for (int q = 0; q < 8; ++q) {
                int cq = cw[q][t];
                cw[q][t] = (unsigned short)run;
                run += cq;
            }
            gofs[t] = (int)(bucketBase[img*NBPI + t] + cntA[(long)c * NBPI + t]) - excl;
        }
    }
    __syncthreads();
    // phase 2: place records into LDS (reuse cached masks — no re-ballot)
    #pragma unroll
    for (int it = 0; it < 8; ++it) {
        long p = qbase + it*64 + lane;
        float iv = image[p];
        float fx = flow[p], fy = flow[HW + p];
        unsigned long long m = mreg[it];
        int l = lreg[it], bkt = l >> 4;
        int cb = __popcll(m & ltmask);
        int ct = __popcll(m);
        int r0 = (int)cw[w][bkt];
        int dst = r0 + cb;
        if (cb == ct - 1) cw[w][bkt] = (unsigned short)(r0 + ct);
        int cx = fx < 0.f ? 0 : (fx == 0.f ? 1 : 2);
        int cy = fy < 0.f ? 0 : (fy == 0.f ? 1 : 2);
        ivs[dst] = iv;
        smeta[dst] = (unsigned short)((bkt << 8) | ((cx * 3 + cy) << 4) | (l & 15));
    }
    __syncthreads();
    // phase 3: linear flush — consecutive j => contiguous global runs
    for (int j = t; j < S; j += 512) {
        int ms = (int)smeta[j];
        int b = ms >> 8;
        int g = gofs[b] + j;
        riv[g]   = ivs[j];
        rmeta[g] = (unsigned char)(ms & 0xFF);
    }
}

// ---- pass 4: fused rank + features, one block per bucket (8 segments) ----
__global__ void __launch_bounds__(512) stageB_kernel(
        const float* __restrict__ riv, const unsigned char* __restrict__ rmeta,
        const unsigned* __restrict__ bucketTotal, const unsigned* __restrict__ bucketBase,
        const int* __restrict__ tabK, const float* __restrict__ tabW,
        float* __restrict__ out, int* __restrict__ lcntg) {
    __shared__ float acc[LPB * NF];          // 12.8 KB
    __shared__ float s_tw[MAXPIX];
    __shared__ int   s_tk[MAXPIX];
    __shared__ int   hist[LPB * 9];
    __shared__ unsigned qc[8][LPB];
    __shared__ int   cur[8][LPB];
    int t = threadIdx.x, w = t >> 6, lane = t & 63;
    int gb = blockIdx.x;
    for (int j = t; j < LPB*NF; j += 512) acc[j] = 0.f;
    for (int j = t; j < MAXPIX; j += 512) { s_tk[j] = tabK[j]; s_tw[j] = tabW[j]; }
    for (int j = t; j < LPB*9; j += 512) hist[j] = 0;
    for (int j = t; j < 8*LPB; j += 512) ((unsigned*)qc)[j] = 0u;
    __syncthreads();
    long base = (long)bucketBase[gb];
    int total = (int)bucketTotal[gb];
    int qsz = (total + 7) >> 3;
    int qbeg = w * qsz, qend = min(qbeg + qsz, total);
    int nit = (qend - qbeg + 63) >> 6;
    // phase 1: per-segment per-label counts (LDS atomics — order-free)
    for (int it = 0; it < nit; ++it) {
        int i = qbeg + it*64 + lane;
        if (i < qend) atomicAdd(&qc[w][rmeta[base + i] & 15], 1u);
    }
    __syncthreads();
    if (t < LPB) {
        int s = 0;
        #pragma unroll
        for (int q = 0; q < 8; ++q) { cur[q][t] = s; s += (int)qc[q][t]; }
        lcntg[gb*LPB + t] = s;
    }
    __syncthreads();
    // phase 2: stable rank + reduce
    for (int it = 0; it < nit; ++it) {
        int i = qbeg + it*64 + lane;
        bool valid = i < qend;
        int meta = valid ? (int)rmeta[base + i] : 0;
        float iv = valid ? riv[base + i] : 0.f;
        int ll = meta & 15, bin = meta >> 4;
        unsigned long long vm = __ballot(valid);
        unsigned long long m = match_bits<4>(ll) & vm;
        if (valid) {
            int cb = __popcll(m & ((1ull << lane) - 1ull));
            int ct = __popcll(m);
            int r0 = cur[w][ll];
            int rank = r0 + cb;
            if (cb == ct - 1) cur[w][ll] = r0 + ct;
            atomicAdd(&hist[ll*9 + bin], 1);
            int k = s_tk[rank];
            if (k >= 0) atomicAdd(&acc[ll*NF + k], iv * s_tw[rank]);  // commutative-exact pair
        }
    }
    __syncthreads();
    if (t < FEAT) {
        for (int r = 0; r < LPB; ++r) {
            long gl = (long)gb * LPB + r;
            out[gl * FEAT + t] = (t < NF) ? acc[r*NF + t] : (float)hist[r*9 + (t - NF)];
        }
    }
}

// ---- pass 5: reduce fz partials -> per-label mean ------------------------
__global__ void __launch_bounds__(512) zfred_kernel(const float* __restrict__ zfpart,
        const int* __restrict__ lcntg, float* __restrict__ zfm) {
    int img = blockIdx.x >> 3;                  // 16 blocks: 2 imgs x 8 segs of 512
    int l = (blockIdx.x & 7) * 512 + threadIdx.x;
    const float* p = zfpart + (long)img * (CBLK/2) * NI + l;
    float s = 0.f;
    for (int b = 0; b < CBLK/2; ++b) s += p[(long)b * NI];
    zfm[img*NI + l] = s / (float)lcntg[img*NI + l];
}

// ---- edges: top-2 nearest centers ----------------------------------------
__device__ __forceinline__ bool better(float d, int j, float d2, int j2) {
    return d < d2 || (d == d2 && j < j2);
}

__global__ void __launch_bounds__(256) edge_kernel(const float* __restrict__ bbox1,
                                                   const float* __restrict__ bbox2,
                                                   const float* __restrict__ zfm,
                                                   float* __restrict__ out) {
    int wave = threadIdx.x >> 6, lane = threadIdx.x & 63;
    int i = blockIdx.x * 4 + wave;
    float c1x = bbox1[i*4 + 0], c1y = bbox1[i*4 + 1];
    float d0 = INFINITY; int j0 = 0x7fffffff;
    float d1 = INFINITY; int j1 = 0x7fffffff;
    for (int t = 0; t < NI; t += 64) {
        int j = t + lane;
        float dx = c1x - bbox2[j*4 + 0];
        float dy = c1y - bbox2[j*4 + 1];
        float dsq = dx*dx + dy*dy;                 // no fma (contract off)
        float d = (float)sqrt((double)dsq);        // correctly-rounded f32 sqrt
        if (better(d, j, d0, j0)) { d1 = d0; j1 = j0; d0 = d; j0 = j; }
        else if (better(d, j, d1, j1)) { d1 = d; j1 = j; }
    }
    for (int off = 32; off; off >>= 1) {
        float od0 = __shfl_down(d0, off); int oj0 = __shfl_down(j0, off);
        float od1 = __shfl_down(d1, off); int oj1 = __shfl_down(j1, off);
        if (better(od0, oj0, d0, j0)) {
            if (better(d0, j0, od1, oj1)) { d1 = d0; j1 = j0; }
            else                          { d1 = od1; j1 = oj1; }
            d0 = od0; j0 = oj0;
        } else if (better(od0, oj0, d1, j1)) { d1 = od0; j1 = oj0; }
    }
    if (lane == 0) {
        float z1 = zfm[i];
        int js[2] = { j0, j1 };
        for (int t = 0; t < 2; ++t) {
            int e = i*2 + t, j = js[t];
            out[EIOFF + e]      = (float)i;
            out[EIOFF + NE + e] = (float)(j + NI);
            float* ea = out + EAOFF + (long)e * 6;
            ea[0] = z1;
            ea[1] = zfm[NI + j];
            ea[2] = c1x - bbox2[j*4 + 0];
            ea[3] = c1y - bbox2[j*4 + 1];
            ea[4] = bbox1[i*4 + 2] / bbox2[j*4 + 2];
            ea[5] = bbox1[i*4 + 3] / bbox2[j*4 + 3];
        }
    }
}

extern "C" void kernel_launch(void* const* d_in, const int* in_sizes, int n_in,
                              void* d_out, int out_size, void* d_ws, size_t ws_size,
                              hipStream_t stream) {
    const float* img1  = (const float*)d_in[0];
    const float* img2  = (const float*)d_in[1];
    const float* flow1 = (const float*)d_in[2];
    const float* flow2 = (const float*)d_in[3];
    const float* bbox1 = (const float*)d_in[4];
    const float* bbox2 = (const float*)d_in[5];
    const int*   mask1 = (const int*)d_in[6];
    const int*   mask2 = (const int*)d_in[7];
    float* out = (float*)d_out;

    char* ws = (char*)d_ws;
    size_t off = 0;
    unsigned* cntA        = (unsigned*)(ws + off); off += (size_t)TOTCHK * NBPI * 4;  // 2 MB
    unsigned* bucketTotal = (unsigned*)(ws + off); off += NBG * 4;
    unsigned* bucketBase  = (unsigned*)(ws + off); off += NBG * 4;
    int*      tabK        = (int*)(ws + off);      off += MAXPIX * 4;
    float*    tabW        = (float*)(ws + off);    off += MAXPIX * 4;
    float*    riv         = (float*)(ws + off);    off += (size_t)REC * 4;            // 67 MB
    float*    zfpart      = (float*)(ws + off);    off += (size_t)CBLK * NI * 4;      // 8.4 MB
    float*    zfm         = (float*)(ws + off);    off += 2 * NI * 4;
    int*      lcntg       = (int*)(ws + off);      off += 2 * NI * 4;
    unsigned char* rmeta  = (unsigned char*)(ws + off); off += (size_t)REC;           // 16.7 MB

    hipLaunchKernelGGL(count_zf_kernel, dim3(CBLK), dim3(256), 0, stream,
                       mask1, mask2, flow1, flow2, cntA, zfpart);
    hipLaunchKernelGGL(scan1_kernel, dim3(NBG), dim3(256), 0, stream, cntA, bucketTotal);
    hipLaunchKernelGGL(scan2_kernel, dim3(1), dim3(NBG), 0, stream, bucketTotal, bucketBase);
    hipLaunchKernelGGL(table_kernel, dim3(1), dim3(256), 0, stream, bucketTotal, tabK, tabW);
    hipLaunchKernelGGL(sort_kernel, dim3(TOTCHK), dim3(512), 0, stream,
                       img1, img2, flow1, flow2, mask1, mask2, cntA, bucketBase,
                       riv, rmeta);
    hipLaunchKernelGGL(stageB_kernel, dim3(NBG), dim3(512), 0, stream,
                       riv, rmeta, bucketTotal, bucketBase, tabK, tabW, out, lcntg);
    hipLaunchKernelGGL(zfred_kernel, dim3(16), dim3(512), 0, stream, zfpart, lcntg, zfm);
    hipLaunchKernelGGL(edge_kernel, dim3(NI/4), dim3(256), 0, stream, bbox1, bbox2, zfm, out);
}